// Round 1
// baseline (1357.882 us; speedup 1.0000x reference)
//
#include <hip/hip_runtime.h>
#include <math.h>
#include <limits.h>

#define NEV 100000
#define NB 8
#define F32EPS 1.1920929e-7f

// ---------------- zero output ----------------
__global__ void k_zero(float* out) {
    if (threadIdx.x == 0) out[0] = 0.0f;
}

// ---------------- t_ref per (batch, polarity, dir) ----------------
// tref[b*4 + mask*2 + dir]; mask 0 = pos(ps==1), 1 = neg; dir 0 = fwd(last), 1 = bwd(first)
__global__ __launch_bounds__(1024) void k_tref(const int* __restrict__ ps,
                                               const float* __restrict__ ts,
                                               float* __restrict__ tref) {
    int b = blockIdx.x;
    const int* p = ps + b * NEV;
    int mnP = INT_MAX, mxP = -1, mnN = INT_MAX, mxN = -1;
    for (int i = threadIdx.x; i < NEV; i += blockDim.x) {
        int v = p[i];
        if (v == 1) { mnP = min(mnP, i); mxP = max(mxP, i); }
        else        { mnN = min(mnN, i); mxN = max(mxN, i); }
    }
    // wave reduce
    for (int o = 32; o > 0; o >>= 1) {
        mnP = min(mnP, __shfl_down(mnP, o, 64));
        mxP = max(mxP, __shfl_down(mxP, o, 64));
        mnN = min(mnN, __shfl_down(mnN, o, 64));
        mxN = max(mxN, __shfl_down(mxN, o, 64));
    }
    __shared__ int s[4];
    if (threadIdx.x == 0) { s[0] = INT_MAX; s[1] = -1; s[2] = INT_MAX; s[3] = -1; }
    __syncthreads();
    if ((threadIdx.x & 63) == 0) {
        atomicMin(&s[0], mnP); atomicMax(&s[1], mxP);
        atomicMin(&s[2], mnN); atomicMax(&s[3], mxN);
    }
    __syncthreads();
    if (threadIdx.x == 0) {
        const float* t = ts + b * NEV;
        int fP = (s[0] == INT_MAX) ? 0 : s[0];
        int lP = (s[1] < 0) ? (NEV - 1) : s[1];
        int fN = (s[2] == INT_MAX) ? 0 : s[2];
        int lN = (s[3] < 0) ? (NEV - 1) : s[3];
        tref[b * 4 + 0] = t[lP];  // pos fwd
        tref[b * 4 + 1] = t[fP];  // pos bwd
        tref[b * 4 + 2] = t[lN];  // neg fwd
        tref[b * 4 + 3] = t[fN];  // neg bwd
    }
}

// ---------------- event splat + per-chunk reduce ----------------
// Block roles per (b, mask): role 0: fi0 whole 32x32; role 1: fi1 whole 64x64;
// roles 2-5: fi2 chunks of 32 rows; roles 6-21: fi3 chunks of 16 rows.
// LDS: 4 planes (dir0 num, dir0 den, dir1 num, dir1 den), planeN <= 4096.
__global__ __launch_bounds__(512) void k_splat(
    const float* __restrict__ f0, const float* __restrict__ f1,
    const float* __restrict__ f2, const float* __restrict__ f3,
    const int* __restrict__ xs, const int* __restrict__ ys,
    const float* __restrict__ ts, const int* __restrict__ ps,
    const float* __restrict__ tref, float* __restrict__ out) {
    __shared__ float acc[16384];  // 64 KB

    int bid = blockIdx.x;
    int b = bid & 7;          // XCD-locality: same batch -> same XCD
    int rest = bid >> 3;      // 0..43
    int mask = rest & 1;
    int role = rest >> 1;     // 0..21

    int fi, row0, nrows;
    if (role == 0)      { fi = 0; row0 = 0; nrows = 32; }
    else if (role == 1) { fi = 1; row0 = 0; nrows = 64; }
    else if (role < 6)  { fi = 2; row0 = (role - 2) * 32; nrows = 32; }
    else                { fi = 3; row0 = (role - 6) * 16; nrows = 16; }

    int W = 32 << fi;             // H == W
    int sh = 3 - fi;
    const float* flow = (fi == 0) ? f0 : (fi == 1) ? f1 : (fi == 2) ? f2 : f3;
    const float* fxp = flow + (size_t)(b * 2 + 0) * W * W;
    const float* fyp = flow + (size_t)(b * 2 + 1) * W * W;
    int planeN = nrows * W;       // 1024 or 4096
    int rowEnd = row0 + nrows;
    float Wm1 = (float)(W - 1);

    for (int i = threadIdx.x; i < 16384; i += blockDim.x) acc[i] = 0.0f;
    __syncthreads();

    float trF = tref[b * 4 + mask * 2 + 0];
    float trB = tref[b * 4 + mask * 2 + 1];
    int want = mask ? -1 : 1;

    const int*   xb = xs + b * NEV;
    const int*   yb = ys + b * NEV;
    const float* tb = ts + b * NEV;
    const int*   pb = ps + b * NEV;

    for (int i = threadIdx.x; i < NEV; i += blockDim.x) {
        if (pb[i] != want) continue;
        int xi = xb[i] >> sh;
        int yi = yb[i] >> sh;
        float t = tb[i];
        float fx = fxp[yi * W + xi];
        float fy = fyp[yi * W + xi];
        #pragma unroll
        for (int dir = 0; dir < 2; ++dir) {
            float t_ = (dir == 0) ? (trF - t + F32EPS) : (trB - t - F32EPS);
            float x_ = fminf(fmaxf((float)xi + t_ * fx, 0.0f), Wm1);
            float y_ = fminf(fmaxf((float)yi + t_ * fy, 0.0f), Wm1);
            float x0f = floorf(x_), y0f = floorf(y_);
            float x1f = x0f + 1.0f, y1f = y0f + 1.0f;
            float x0w = x_ - x0f, x1w = x1f - x_;
            float y0w = y_ - y0f, y1w = y1f - y_;
            int x0i = (int)x0f, y0i = (int)y0f;
            int x1i = (int)fminf(x1f, Wm1);
            int y1i = (int)fminf(y1f, Wm1);
            float Ta = x0w * y0w * t;  // -> (x1i, y1i)
            float Tb_ = x1w * y0w * t; // -> (x0i, y1i)
            float Tc = x0w * y1w * t;  // -> (x1i, y0i)
            float Td = x1w * y1w * t;  // -> (x0i, y0i)
            float* num = acc + dir * 8192;
            float* den = num + planeN;
            if (y1i >= row0 && y1i < rowEnd) {
                int r = (y1i - row0) * W;
                atomicAdd(&num[r + x1i], Ta);  atomicAdd(&den[r + x1i], 1.0f);
                atomicAdd(&num[r + x0i], Tb_); atomicAdd(&den[r + x0i], 1.0f);
            }
            if (y0i >= row0 && y0i < rowEnd) {
                int r = (y0i - row0) * W;
                atomicAdd(&num[r + x1i], Tc);  atomicAdd(&den[r + x1i], 1.0f);
                atomicAdd(&num[r + x0i], Td);  atomicAdd(&den[r + x0i], 1.0f);
            }
        }
    }
    __syncthreads();

    float s = 0.0f;
    for (int off = threadIdx.x; off < planeN; off += blockDim.x) {
        #pragma unroll
        for (int dir = 0; dir < 2; ++dir) {
            float num = acc[dir * 8192 + off];
            float den = acc[dir * 8192 + planeN + off];
            float r = num / (den + F32EPS);
            s += sqrtf(r * r + 1e-6f);
        }
    }
    for (int o = 32; o > 0; o >>= 1) s += __shfl_down(s, o, 64);
    int wave = threadIdx.x >> 6;
    __syncthreads();                      // done reading acc; reuse for reduction
    if ((threadIdx.x & 63) == 0) acc[wave] = s;
    __syncthreads();
    if (threadIdx.x == 0) {
        float tot = 0.0f;
        int nw = blockDim.x >> 6;
        for (int w = 0; w < nw; ++w) tot += acc[w];
        atomicAdd(out, tot);
    }
}

// ---------------- weight decay: sum(p^2) * 5e-5 ----------------
__global__ void k_wd(const float* __restrict__ p, int n, float* __restrict__ out) {
    float s = 0.0f;
    int n4 = n >> 2;
    const float4* p4 = (const float4*)p;
    for (int i = blockIdx.x * blockDim.x + threadIdx.x; i < n4; i += gridDim.x * blockDim.x) {
        float4 v = p4[i];
        s += v.x * v.x + v.y * v.y + v.z * v.z + v.w * v.w;
    }
    // tail (n % 4), handled by thread 0 of block 0
    if (blockIdx.x == 0 && threadIdx.x == 0) {
        for (int i = n4 * 4; i < n; ++i) s += p[i] * p[i];
    }
    for (int o = 32; o > 0; o >>= 1) s += __shfl_down(s, o, 64);
    __shared__ float red[16];
    if ((threadIdx.x & 63) == 0) red[threadIdx.x >> 6] = s;
    __syncthreads();
    if (threadIdx.x == 0) {
        float t = 0.0f;
        int nw = blockDim.x >> 6;
        for (int w = 0; w < nw; ++w) t += red[w];
        atomicAdd(out, t * 5e-5f);
    }
}

// ---------------- smoothness (one flow; H == W == 1<<logW) ----------------
// contribution = 6.25 * (mean_lr + mean_ud + mean_d1 + mean_d2)
__global__ void k_smooth(const float* __restrict__ f, int logW, float* __restrict__ out) {
    int W = 1 << logW;
    int n = 16 * W * W;  // B*2*H*W
    float c_lr = 6.25f / (float)(16 * W * (W - 1));
    float c_ud = c_lr;                              // same count (H==W)
    float c_dd = 6.25f / (float)(16 * (W - 1) * (W - 1));
    float s = 0.0f;
    for (int idx = blockIdx.x * blockDim.x + threadIdx.x; idx < n; idx += gridDim.x * blockDim.x) {
        int x = idx & (W - 1);
        int y = (idx >> logW) & (W - 1);
        float v = f[idx];
        bool xok = x < W - 1;
        bool yok = y < W - 1;
        float vr = xok ? f[idx + 1] : 0.0f;
        float vd = yok ? f[idx + W] : 0.0f;
        if (xok) { float d = vr - v; s += c_lr * powf(d * d + 1e-6f, 0.45f); }
        if (yok) { float d = vd - v; s += c_ud * powf(d * d + 1e-6f, 0.45f); }
        if (xok && yok) {
            float d1 = f[idx + W + 1] - v;
            s += c_dd * powf(d1 * d1 + 1e-6f, 0.45f);
            float d2 = vr - vd;
            s += c_dd * powf(d2 * d2 + 1e-6f, 0.45f);
        }
    }
    for (int o = 32; o > 0; o >>= 1) s += __shfl_down(s, o, 64);
    __shared__ float red[16];
    if ((threadIdx.x & 63) == 0) red[threadIdx.x >> 6] = s;
    __syncthreads();
    if (threadIdx.x == 0) {
        float t = 0.0f;
        int nw = blockDim.x >> 6;
        for (int w = 0; w < nw; ++w) t += red[w];
        atomicAdd(out, t);
    }
}

extern "C" void kernel_launch(void* const* d_in, const int* in_sizes, int n_in,
                              void* d_out, int out_size, void* d_ws, size_t ws_size,
                              hipStream_t stream) {
    const float* f0 = (const float*)d_in[0];
    const float* f1 = (const float*)d_in[1];
    const float* f2 = (const float*)d_in[2];
    const float* f3 = (const float*)d_in[3];
    const int*   xs = (const int*)d_in[4];
    const int*   ys = (const int*)d_in[5];
    const float* ts = (const float*)d_in[6];
    const int*   ps = (const int*)d_in[7];
    const float* params = (const float*)d_in[10];
    float* out  = (float*)d_out;
    float* tref = (float*)d_ws;  // 32 floats

    hipLaunchKernelGGL(k_zero, dim3(1), dim3(64), 0, stream, out);
    hipLaunchKernelGGL(k_tref, dim3(NB), dim3(1024), 0, stream, ps, ts, tref);
    hipLaunchKernelGGL(k_splat, dim3(352), dim3(512), 0, stream,
                       f0, f1, f2, f3, xs, ys, ts, ps, tref, out);
    hipLaunchKernelGGL(k_wd, dim3(512), dim3(256), 0, stream, params, in_sizes[10], out);
    hipLaunchKernelGGL(k_smooth, dim3(256), dim3(256), 0, stream, f0, 5, out);
    hipLaunchKernelGGL(k_smooth, dim3(256), dim3(256), 0, stream, f1, 6, out);
    hipLaunchKernelGGL(k_smooth, dim3(256), dim3(256), 0, stream, f2, 7, out);
    hipLaunchKernelGGL(k_smooth, dim3(256), dim3(256), 0, stream, f3, 8, out);
}